// Round 1
// baseline (1939.848 us; speedup 1.0000x reference)
//
#include <hip/hip_runtime.h>

#define B_ 2
#define H_ 16
#define S_ 2048
#define D_ 128

typedef __attribute__((ext_vector_type(8))) short short8;
typedef __attribute__((ext_vector_type(4))) float floatx4;

__device__ __forceinline__ unsigned short f2bf(float f) {
    union { float f; unsigned int u; } c; c.f = f;
    unsigned int u = c.u;
    u += 0x7fff + ((u >> 16) & 1);   // round-to-nearest-even
    return (unsigned short)(u >> 16);
}

// ---------------------------------------------------------------------------
// Kernel 0: V (fp32 [bh][s][d]) -> V^T (bf16 [bh][d][s]) in workspace.
// Needed so PV's B-operand fragments are 8 contiguous keys (ds_read_b128).
// ---------------------------------------------------------------------------
__global__ __launch_bounds__(256) void vt_kernel(const float* __restrict__ v,
                                                 unsigned short* __restrict__ vt) {
    __shared__ unsigned short tl[128][66];   // pad 2 -> uint-aligned reads
    int bid = blockIdx.x;
    int bh = bid >> 5;            // / 32
    int s0 = (bid & 31) << 6;     // * 64
    int t = threadIdx.x;
    const float4* vp = (const float4*)(v + ((size_t)bh * S_ + s0) * D_);
    #pragma unroll
    for (int i = 0; i < 8; ++i) {
        int idx = t + i * 256;          // 2048 float4 = 64 rows x 32
        int r = idx >> 5;
        int d = (idx & 31) << 2;
        float4 x = vp[idx];
        tl[d + 0][r] = f2bf(x.x);
        tl[d + 1][r] = f2bf(x.y);
        tl[d + 2][r] = f2bf(x.z);
        tl[d + 3][r] = f2bf(x.w);
    }
    __syncthreads();
    unsigned short* op = vt + (size_t)bh * D_ * S_ + s0;
    #pragma unroll
    for (int i = 0; i < 16; ++i) {
        int idx = t + i * 256;          // 4096 uint = 128 rows x 32
        int d = idx >> 5;
        int s2 = (idx & 31) << 1;
        unsigned int val = (unsigned int)tl[d][s2] | ((unsigned int)tl[d][s2 + 1] << 16);
        *(unsigned int*)(op + (size_t)d * S_ + s2) = val;
    }
}

// ---------------------------------------------------------------------------
// Kernel 1: e = exp(QK^T*scale + bias) masked, written unnormalized to attn;
// per-row sums l -> ws. Block = (b,h) x 64 q-rows; K-loop tiles of 128 keys.
// ---------------------------------------------------------------------------
__global__ __launch_bounds__(256) void qk_kernel(const float* __restrict__ q,
                                                 const float* __restrict__ k,
                                                 const int* __restrict__ mask,
                                                 const float* __restrict__ bias,
                                                 float* __restrict__ attn,
                                                 float* __restrict__ lsum) {
    __shared__ unsigned short q_lds[64 * 136];    // bf16, row pad 136
    __shared__ unsigned short k_lds[128 * 136];
    int bid = blockIdx.x;
    int qt = bid >> 5;            // q-tile outer: mask/bias tiles reused by
    int hb = bid & 31;            // the 32 adjacent (h,b) blocks via L2/L3
    int h = hb >> 1;
    int b = hb & 1;
    int bh = b * H_ + h;
    int q0 = qt << 6;
    int t = threadIdx.x;
    int w = t >> 6;
    int lane = t & 63;
    int g = lane >> 4;
    int l16 = lane & 15;

    // stage Q tile 64x128 fp32 -> bf16 LDS
    const float4* qp = (const float4*)(q + ((size_t)bh * S_ + q0) * D_);
    #pragma unroll
    for (int i = 0; i < 8; ++i) {
        int idx = t + i * 256;
        int r = idx >> 5;
        int d = (idx & 31) << 2;
        float4 x = qp[idx];
        ushort4 y;
        y.x = f2bf(x.x); y.y = f2bf(x.y); y.z = f2bf(x.z); y.w = f2bf(x.w);
        *(ushort4*)&q_lds[r * 136 + d] = y;
    }
    __syncthreads();

    // A-fragments are K-loop invariant: hoist. A[m=l16][k=g*8+j]
    short8 afr[4];
    {
        int ro = (w * 16 + l16) * 136 + g * 8;
        #pragma unroll
        for (int kk = 0; kk < 4; ++kk)
            afr[kk] = *(const short8*)&q_lds[ro + kk * 32];
    }

    const float scale = 0.08838834764831845f;  // 1/sqrt(128)
    float rs[4] = {0.f, 0.f, 0.f, 0.f};
    const float* bias_h = bias + (size_t)h * S_ * S_;
    const int* mask_b = mask + (size_t)b * S_ * S_;
    float* attn_p = attn + (size_t)bh * S_ * S_;
    const float4* kbase = (const float4*)(k + (size_t)bh * S_ * D_);

    for (int kt = 0; kt < 16; ++kt) {
        int k0 = kt << 7;
        __syncthreads();
        // stage K tile 128x128 fp32 -> bf16 LDS
        const float4* kp = kbase + (size_t)k0 * (D_ / 4);
        #pragma unroll
        for (int i = 0; i < 16; ++i) {
            int idx = t + i * 256;
            int r = idx >> 5;
            int d = (idx & 31) << 2;
            float4 x = kp[idx];
            ushort4 y;
            y.x = f2bf(x.x); y.y = f2bf(x.y); y.z = f2bf(x.z); y.w = f2bf(x.w);
            *(ushort4*)&k_lds[r * 136 + d] = y;
        }
        __syncthreads();

        #pragma unroll
        for (int nt = 0; nt < 8; ++nt) {
            floatx4 acc = {0.f, 0.f, 0.f, 0.f};
            int bro = (nt * 16 + l16) * 136 + g * 8;
            #pragma unroll
            for (int kk = 0; kk < 4; ++kk) {
                short8 bfr = *(const short8*)&k_lds[bro + kk * 32];
                acc = __builtin_amdgcn_mfma_f32_16x16x32_bf16(afr[kk], bfr, acc, 0, 0, 0);
            }
            // C/D layout: col=l16, row=g*4+r
            int col = k0 + nt * 16 + l16;
            int rowb = q0 + w * 16 + g * 4;
            #pragma unroll
            for (int r = 0; r < 4; ++r) {
                int row = rowb + r;
                float s = acc[r] * scale + bias_h[(size_t)row * S_ + col];
                int m = mask_b[(size_t)row * S_ + col];
                float e = m ? __expf(s) : 0.0f;   // fixed-ref softmax: no max pass
                attn_p[(size_t)row * S_ + col] = e;
                rs[r] += e;
            }
        }
    }

    // row sums: reduce across the 16 lanes holding one row group
    #pragma unroll
    for (int r = 0; r < 4; ++r) {
        #pragma unroll
        for (int off = 1; off < 16; off <<= 1)
            rs[r] += __shfl_xor(rs[r], off, 16);
    }
    if (l16 == 0) {
        float* lp = lsum + (size_t)bh * S_ + q0 + w * 16 + g * 4;
        lp[0] = rs[0]; lp[1] = rs[1]; lp[2] = rs[2]; lp[3] = rs[3];
    }
}

// ---------------------------------------------------------------------------
// Kernel 2: p = e/l (rewrite attn normalized in place), out = p @ V via MFMA
// against the pre-transposed bf16 V^T tiles.
// ---------------------------------------------------------------------------
__global__ __launch_bounds__(256) void pv_kernel(float* __restrict__ attn,
                                                 const unsigned short* __restrict__ vt,
                                                 const float* __restrict__ lsum,
                                                 float* __restrict__ out) {
    __shared__ unsigned short p_lds[64 * 136];
    __shared__ unsigned short v_lds[128 * 136];
    __shared__ float rinv[64];
    int bid = blockIdx.x;
    int qt = bid >> 5;
    int hb = bid & 31;
    int h = hb >> 1;
    int b = hb & 1;
    int bh = b * H_ + h;
    int q0 = qt << 6;
    int t = threadIdx.x;
    int w = t >> 6;
    int lane = t & 63;
    int g = lane >> 4;
    int l16 = lane & 15;

    if (t < 64) {
        float lv = lsum[(size_t)bh * S_ + q0 + t];
        rinv[t] = lv > 0.f ? 1.0f / lv : 0.0f;
    }

    floatx4 acc[8];
    #pragma unroll
    for (int nt = 0; nt < 8; ++nt) acc[nt] = (floatx4){0.f, 0.f, 0.f, 0.f};

    float* attn_p = attn + ((size_t)bh * S_ + q0) * S_;
    const unsigned short* vt_p = vt + (size_t)bh * D_ * S_;

    for (int kt = 0; kt < 16; ++kt) {
        int k0 = kt << 7;
        __syncthreads();   // covers rinv (kt=0) and LDS reuse (kt>0)
        // stage P tile: read e, normalize, write back, bf16 -> LDS
        #pragma unroll
        for (int i = 0; i < 8; ++i) {
            int idx = t + i * 256;
            int r = idx >> 5;
            int c = (idx & 31) << 2;
            float4* gp = (float4*)(attn_p + (size_t)r * S_ + k0 + c);
            float4 x = *gp;
            float riv = rinv[r];
            x.x *= riv; x.y *= riv; x.z *= riv; x.w *= riv;
            *gp = x;
            ushort4 y;
            y.x = f2bf(x.x); y.y = f2bf(x.y); y.z = f2bf(x.z); y.w = f2bf(x.w);
            *(ushort4*)&p_lds[r * 136 + c] = y;
        }
        // stage V^T tile 128(d) x 128(key) bf16
        #pragma unroll
        for (int i = 0; i < 8; ++i) {
            int idx = t + i * 256;          // 2048 chunks of 8 bf16
            int d = idx >> 4;
            int c8 = (idx & 15) << 3;
            uint4 val = *(const uint4*)(vt_p + (size_t)d * S_ + k0 + c8);
            *(uint4*)&v_lds[d * 136 + c8] = val;
        }
        __syncthreads();

        int aro = (w * 16 + l16) * 136 + g * 8;
        #pragma unroll
        for (int kk = 0; kk < 4; ++kk) {
            short8 afr = *(const short8*)&p_lds[aro + kk * 32];
            #pragma unroll
            for (int nt = 0; nt < 8; ++nt) {
                short8 bfr = *(const short8*)&v_lds[(nt * 16 + l16) * 136 + kk * 32 + g * 8];
                acc[nt] = __builtin_amdgcn_mfma_f32_16x16x32_bf16(afr, bfr, acc[nt], 0, 0, 0);
            }
        }
    }

    float* op = out + ((size_t)bh * S_ + q0 + w * 16 + g * 4) * D_ + l16;
    #pragma unroll
    for (int nt = 0; nt < 8; ++nt)
        #pragma unroll
        for (int r = 0; r < 4; ++r)
            op[(size_t)r * D_ + nt * 16] = acc[nt][r];
}

extern "C" void kernel_launch(void* const* d_in, const int* in_sizes, int n_in,
                              void* d_out, int out_size, void* d_ws, size_t ws_size,
                              hipStream_t stream) {
    const float* q    = (const float*)d_in[0];
    const float* k    = (const float*)d_in[1];
    const float* v    = (const float*)d_in[2];
    const int*   mask = (const int*)d_in[3];
    const float* bias = (const float*)d_in[4];

    float* out  = (float*)d_out;
    float* attn = out + (size_t)B_ * H_ * S_ * D_;   // outputs concatenated

    // ws: [0, 512KB) row sums l; [512KB, +16.8MB) V^T bf16
    float* lsum = (float*)d_ws;
    unsigned short* vt = (unsigned short*)((char*)d_ws + (size_t)B_ * H_ * S_ * sizeof(float));

    int nblk = B_ * H_ * (S_ / 64);   // 1024
    vt_kernel<<<nblk, 256, 0, stream>>>(v, vt);
    qk_kernel<<<nblk, 256, 0, stream>>>(q, k, mask, bias, attn, lsum);
    pv_kernel<<<nblk, 256, 0, stream>>>(attn, vt, lsum, out);
}

// Round 2
// 1275.179 us; speedup vs baseline: 1.5212x; 1.5212x over previous
//
#include <hip/hip_runtime.h>

#define B_ 2
#define H_ 16
#define S_ 2048
#define D_ 128

typedef __attribute__((ext_vector_type(8))) short short8;
typedef __attribute__((ext_vector_type(4))) float floatx4;

__device__ __forceinline__ unsigned short f2bf(float f) {
    union { float f; unsigned int u; } c; c.f = f;
    unsigned int u = c.u;
    u += 0x7fff + ((u >> 16) & 1);   // round-to-nearest-even
    return (unsigned short)(u >> 16);
}

// ---------------------------------------------------------------------------
// Kernel 0: V (fp32 [bh][s][d]) -> V^T (bf16 [bh][d][s]) in workspace.
// ---------------------------------------------------------------------------
__global__ __launch_bounds__(256) void vt_kernel(const float* __restrict__ v,
                                                 unsigned short* __restrict__ vt) {
    __shared__ unsigned short tl[128][66];
    int bid = blockIdx.x;
    int bh = bid >> 5;
    int s0 = (bid & 31) << 6;
    int t = threadIdx.x;
    const float4* vp = (const float4*)(v + ((size_t)bh * S_ + s0) * D_);
    #pragma unroll
    for (int i = 0; i < 8; ++i) {
        int idx = t + i * 256;
        int r = idx >> 5;
        int d = (idx & 31) << 2;
        float4 x = vp[idx];
        tl[d + 0][r] = f2bf(x.x);
        tl[d + 1][r] = f2bf(x.y);
        tl[d + 2][r] = f2bf(x.z);
        tl[d + 3][r] = f2bf(x.w);
    }
    __syncthreads();
    unsigned short* op = vt + (size_t)bh * D_ * S_ + s0;
    #pragma unroll
    for (int i = 0; i < 16; ++i) {
        int idx = t + i * 256;
        int d = idx >> 5;
        int s2 = (idx & 31) << 1;
        unsigned int val = (unsigned int)tl[d][s2] | ((unsigned int)tl[d][s2 + 1] << 16);
        *(unsigned int*)(op + (size_t)d * S_ + s2) = val;
    }
}

// ---------------------------------------------------------------------------
// Kernel 1: e = exp(QK^T*scale + bias) masked -> attn (unnormalized), row
// sums -> lsum.  BK=64 key tiles; scores round-trip through LDS so that all
// bias/mask/attn global traffic is coalesced float4; bias/mask prefetched
// into registers during K staging to hide HBM latency under MFMA.
// ---------------------------------------------------------------------------
__global__ __launch_bounds__(256, 4) void qk_kernel(const float* __restrict__ q,
                                                    const float* __restrict__ k,
                                                    const int* __restrict__ mask,
                                                    const float* __restrict__ bias,
                                                    float* __restrict__ attn,
                                                    float* __restrict__ lsum) {
    __shared__ unsigned short q_lds[64 * 136];          // 17408 B
    __shared__ __align__(16) char ks[17408];            // k_lds bf16 64x136  |  s_lds f32 64x68
    unsigned short* k_lds = (unsigned short*)ks;
    float* s_lds = (float*)ks;

    int bid = blockIdx.x;
    int qt = bid >> 5;
    int hb = bid & 31;
    int h = hb >> 1;
    int b = hb & 1;
    int bh = b * H_ + h;
    int q0 = qt << 6;
    int t = threadIdx.x;
    int w = t >> 6;
    int lane = t & 63;
    int g = lane >> 4;
    int l16 = lane & 15;
    int tr = t >> 4;            // 0..15: epilogue row group
    int tc = (t & 15) << 2;     // epilogue col (float4)

    // stage Q tile 64x128 fp32 -> bf16 LDS
    const float4* qp = (const float4*)(q + ((size_t)bh * S_ + q0) * D_);
    #pragma unroll
    for (int i = 0; i < 8; ++i) {
        int idx = t + i * 256;
        int r = idx >> 5;
        int d = (idx & 31) << 2;
        float4 x = qp[idx];
        ushort4 y;
        y.x = f2bf(x.x); y.y = f2bf(x.y); y.z = f2bf(x.z); y.w = f2bf(x.w);
        *(ushort4*)&q_lds[r * 136 + d] = y;
    }
    __syncthreads();

    // A-fragments are loop-invariant: A[m=l16][k=g*8+j]
    short8 afr[4];
    {
        int ro = (w * 16 + l16) * 136 + g * 8;
        #pragma unroll
        for (int kk = 0; kk < 4; ++kk)
            afr[kk] = *(const short8*)&q_lds[ro + kk * 32];
    }

    const float scale = 0.08838834764831845f;  // 1/sqrt(128)
    float rs[4] = {0.f, 0.f, 0.f, 0.f};
    const float* bias_h = bias + (size_t)h * S_ * S_;
    const int* mask_b = mask + (size_t)b * S_ * S_;
    float* attn_p = attn + (size_t)bh * S_ * S_;
    const float4* kbase = (const float4*)(k + (size_t)bh * S_ * D_);

    for (int kt = 0; kt < 32; ++kt) {
        int k0 = kt << 6;
        __syncthreads();
        // issue K-tile loads (64 rows x 128 d)
        const float4* kp = kbase + (size_t)k0 * (D_ / 4);
        float4 kv[8];
        #pragma unroll
        for (int i = 0; i < 8; ++i) kv[i] = kp[t + i * 256];
        // prefetch bias/mask for this k-tile (coalesced float4/int4);
        // latency hides under K staging + MFMA
        float4 b4[4];
        int4 m4[4];
        #pragma unroll
        for (int i = 0; i < 4; ++i) {
            size_t off = (size_t)(q0 + tr + 16 * i) * S_ + k0 + tc;
            b4[i] = *(const float4*)&bias_h[off];
            m4[i] = *(const int4*)&mask_b[off];
        }
        // convert + store K tile to LDS
        #pragma unroll
        for (int i = 0; i < 8; ++i) {
            int idx = t + i * 256;
            int r = idx >> 5;
            int d = (idx & 31) << 2;
            ushort4 y;
            y.x = f2bf(kv[i].x); y.y = f2bf(kv[i].y); y.z = f2bf(kv[i].z); y.w = f2bf(kv[i].w);
            *(ushort4*)&k_lds[r * 136 + d] = y;
        }
        __syncthreads();

        floatx4 acc[4];
        #pragma unroll
        for (int nt = 0; nt < 4; ++nt) acc[nt] = (floatx4){0.f, 0.f, 0.f, 0.f};
        #pragma unroll
        for (int kk = 0; kk < 4; ++kk) {
            #pragma unroll
            for (int nt = 0; nt < 4; ++nt) {
                short8 bfr = *(const short8*)&k_lds[(nt * 16 + l16) * 136 + kk * 32 + g * 8];
                acc[nt] = __builtin_amdgcn_mfma_f32_16x16x32_bf16(afr[kk], bfr, acc[nt], 0, 0, 0);
            }
        }
        __syncthreads();   // all waves done reading k_lds before aliasing as s_lds

        // write scores to LDS: local row = w*16+g*4+r, local col = nt*16+l16
        #pragma unroll
        for (int nt = 0; nt < 4; ++nt)
            #pragma unroll
            for (int r = 0; r < 4; ++r)
                s_lds[(w * 16 + g * 4 + r) * 68 + nt * 16 + l16] = acc[nt][r];
        __syncthreads();

        // epilogue: fully coalesced float4 exp + store + rowsum partials
        #pragma unroll
        for (int i = 0; i < 4; ++i) {
            int lr = tr + 16 * i;
            float4 sv = *(const float4*)&s_lds[lr * 68 + tc];
            float4 e;
            e.x = m4[i].x ? __expf(fmaf(sv.x, scale, b4[i].x)) : 0.f;
            e.y = m4[i].y ? __expf(fmaf(sv.y, scale, b4[i].y)) : 0.f;
            e.z = m4[i].z ? __expf(fmaf(sv.z, scale, b4[i].z)) : 0.f;
            e.w = m4[i].w ? __expf(fmaf(sv.w, scale, b4[i].w)) : 0.f;
            *(float4*)&attn_p[(size_t)(q0 + lr) * S_ + k0 + tc] = e;
            rs[i] += (e.x + e.y) + (e.z + e.w);
        }
    }

    // reduce rowsums across the 16 lanes sharing a row
    #pragma unroll
    for (int i = 0; i < 4; ++i) {
        #pragma unroll
        for (int off = 1; off < 16; off <<= 1)
            rs[i] += __shfl_xor(rs[i], off, 16);
        if ((t & 15) == 0)
            lsum[(size_t)bh * S_ + q0 + tr + 16 * i] = rs[i];
    }
}

// ---------------------------------------------------------------------------
// Kernel 2: p = e/l (normalized attn written in place), out = p @ V.
// BK=64 key tiles for smaller LDS -> higher occupancy.
// ---------------------------------------------------------------------------
__global__ __launch_bounds__(256, 4) void pv_kernel(float* __restrict__ attn,
                                                    const unsigned short* __restrict__ vt,
                                                    const float* __restrict__ lsum,
                                                    float* __restrict__ out) {
    __shared__ unsigned short p_lds[64 * 80];    // rows padded to 80 shorts (160B, 16B-aligned)
    __shared__ unsigned short v_lds[128 * 80];
    __shared__ float rinv[64];
    int bid = blockIdx.x;
    int qt = bid >> 5;
    int hb = bid & 31;
    int h = hb >> 1;
    int b = hb & 1;
    int bh = b * H_ + h;
    int q0 = qt << 6;
    int t = threadIdx.x;
    int w = t >> 6;
    int lane = t & 63;
    int g = lane >> 4;
    int l16 = lane & 15;
    int tr = t >> 4;
    int tc = (t & 15) << 2;

    if (t < 64) {
        float lv = lsum[(size_t)bh * S_ + q0 + t];
        rinv[t] = lv > 0.f ? 1.0f / lv : 0.0f;
    }
    __syncthreads();

    floatx4 acc[8];
    #pragma unroll
    for (int nt = 0; nt < 8; ++nt) acc[nt] = (floatx4){0.f, 0.f, 0.f, 0.f};

    float* attn_p = attn + ((size_t)bh * S_ + q0) * S_;
    const unsigned short* vt_p = vt + (size_t)bh * D_ * S_;

    for (int kt = 0; kt < 32; ++kt) {
        int k0 = kt << 6;
        __syncthreads();
        // stage P tile 64x64: read e, normalize, write back, bf16 -> LDS
        #pragma unroll
        for (int i = 0; i < 4; ++i) {
            int lr = tr + 16 * i;
            float4* gp = (float4*)&attn_p[(size_t)lr * S_ + k0 + tc];
            float4 x = *gp;
            float riv = rinv[lr];
            x.x *= riv; x.y *= riv; x.z *= riv; x.w *= riv;
            *gp = x;
            ushort4 y;
            y.x = f2bf(x.x); y.y = f2bf(x.y); y.z = f2bf(x.z); y.w = f2bf(x.w);
            *(ushort4*)&p_lds[lr * 80 + tc] = y;
        }
        // stage V^T tile 128(d) x 64(key)
        #pragma unroll
        for (int i = 0; i < 4; ++i) {
            int idx = t + i * 256;      // 1024 uint4
            int d = idx >> 3;
            int c8 = (idx & 7) << 3;
            *(uint4*)&v_lds[d * 80 + c8] = *(const uint4*)&vt_p[(size_t)d * S_ + k0 + c8];
        }
        __syncthreads();

        #pragma unroll
        for (int kk = 0; kk < 2; ++kk) {
            short8 afr = *(const short8*)&p_lds[(w * 16 + l16) * 80 + kk * 32 + g * 8];
            #pragma unroll
            for (int nt = 0; nt < 8; ++nt) {
                short8 bfr = *(const short8*)&v_lds[(nt * 16 + l16) * 80 + kk * 32 + g * 8];
                acc[nt] = __builtin_amdgcn_mfma_f32_16x16x32_bf16(afr, bfr, acc[nt], 0, 0, 0);
            }
        }
    }

    float* op = out + ((size_t)bh * S_ + q0 + w * 16 + g * 4) * D_ + l16;
    #pragma unroll
    for (int nt = 0; nt < 8; ++nt)
        #pragma unroll
        for (int r = 0; r < 4; ++r)
            op[(size_t)r * D_ + nt * 16] = acc[nt][r];
}

extern "C" void kernel_launch(void* const* d_in, const int* in_sizes, int n_in,
                              void* d_out, int out_size, void* d_ws, size_t ws_size,
                              hipStream_t stream) {
    const float* q    = (const float*)d_in[0];
    const float* k    = (const float*)d_in[1];
    const float* v    = (const float*)d_in[2];
    const int*   mask = (const int*)d_in[3];
    const float* bias = (const float*)d_in[4];

    float* out  = (float*)d_out;
    float* attn = out + (size_t)B_ * H_ * S_ * D_;

    float* lsum = (float*)d_ws;
    unsigned short* vt = (unsigned short*)((char*)d_ws + (size_t)B_ * H_ * S_ * sizeof(float));

    int nblk = B_ * H_ * (S_ / 64);   // 1024
    vt_kernel<<<nblk, 256, 0, stream>>>(v, vt);
    qk_kernel<<<nblk, 256, 0, stream>>>(q, k, mask, bias, attn, lsum);
    pv_kernel<<<nblk, 256, 0, stream>>>(attn, vt, lsum, out);
}